// Round 3
// baseline (127724.451 us; speedup 1.0000x reference)
//
#include <hip/hip_runtime.h>
#include <math.h>

namespace {

constexpr int cH  = 1024;
constexpr int cZ  = 256;
constexpr int cB  = 64;
constexpr int cT  = 256;
constexpr int cR  = 389;
constexpr int cSC = 89;
constexpr int cPF = 300;
constexpr int cIN0 = 645;              // PERF + SCORE + Z
constexpr int ISTR = 648;              // padded layer-0 input stride (floats), 16B aligned
constexpr float INV_S = 0.9999950000374997f;  // 1/sqrt(1+1e-5)
constexpr unsigned NBLK = 256;         // persistent grid size (1 block/CU)

__device__ __forceinline__ void fma4(float4& a, const float4 x, const float4 w){
  a.x = fmaf(x.x, w.x, a.x);
  a.y = fmaf(x.y, w.y, a.y);
  a.z = fmaf(x.z, w.z, a.z);
  a.w = fmaf(x.w, w.w, a.w);
}
__device__ __forceinline__ float fold4(const float4 a){ return (a.x + a.y) + (a.z + a.w); }
__device__ __forceinline__ float4 z4(){ return make_float4(0.f, 0.f, 0.f, 0.f); }
__device__ __forceinline__ float sigm(float x){ return 1.f / (1.f + expf(-x)); }

// device-scope sense-counting grid barrier (all NBLK blocks must be resident;
// grid = 256 blocks = 1/CU with __launch_bounds__(512,2) guarantees that).
__device__ __forceinline__ void gbar(unsigned* cnt, unsigned* gen, unsigned nb){
  __syncthreads();
  if (threadIdx.x == 0){
    __threadfence();                                   // release our stores agent-wide
    unsigned g = __hip_atomic_load(gen, __ATOMIC_RELAXED, __HIP_MEMORY_SCOPE_AGENT);
    unsigned a = __hip_atomic_fetch_add(cnt, 1u, __ATOMIC_ACQ_REL, __HIP_MEMORY_SCOPE_AGENT);
    if (a == nb - 1u){
      __hip_atomic_store(cnt, 0u, __ATOMIC_RELAXED, __HIP_MEMORY_SCOPE_AGENT);
      __hip_atomic_store(gen, g + 1u, __ATOMIC_RELEASE, __HIP_MEMORY_SCOPE_AGENT);
    } else {
      while (__hip_atomic_load(gen, __ATOMIC_RELAXED, __HIP_MEMORY_SCOPE_AGENT) == g)
        __builtin_amdgcn_s_sleep(2);
    }
    __threadfence();                                   // acquire remote stores
  }
  __syncthreads();
}

// ---------------------------------------------------------------- init / prep
__global__ __launch_bounds__(256) void init_kernel(float* hf0, float* hb0, float* dout_tail,
                                                   unsigned* bar){
  const int idx = blockIdx.x * 256 + threadIdx.x;
  const int stride = gridDim.x * 256;
  for (int i = idx; i < cB * cH; i += stride){ hf0[i] = 0.f; hb0[i] = 0.f; }
  for (int i = idx; i < 2 * cB * cZ; i += stride) dout_tail[i] = 0.f;
  if (idx < 64) bar[idx] = 0u;   // barrier cnt/gen slots (cache-line spaced)
}

__global__ __launch_bounds__(256) void pad_w0_kernel(const float* __restrict__ w,
                                                     float* __restrict__ wp){
  const int idx = blockIdx.x * 256 + threadIdx.x;
  const int stride = gridDim.x * 256;
  const int n = 3 * cH * ISTR;
  for (int i = idx; i < n; i += stride){
    const int r = i / ISTR;
    const int c = i - r * ISTR;
    wp[i] = (c < cIN0) ? w[(size_t)r * cIN0 + c] : 0.f;
  }
}

// ---------------------------------------------------------------- encoder (persistent)
// 256 blocks x 512 thr: dir = bid>>7, bhalf = (bid>>6)&1, kblk = bid&63 (16 k-rows).
// threads: dseg = (tid>>6)&3 (4-way d split), khalf = tid>>8, lane 64: tx->4 batches, ty->k.
__global__ __launch_bounds__(512, 2) void enc_persist(
    const float* __restrict__ x,
    const float* __restrict__ wih_f, const float* __restrict__ whh_f,
    const float* __restrict__ bih_f, const float* __restrict__ bhh_f,
    const float* __restrict__ wih_b, const float* __restrict__ whh_b,
    const float* __restrict__ bih_b, const float* __restrict__ bhh_b,
    float* __restrict__ hfA, float* __restrict__ hfB,
    float* __restrict__ hbA, float* __restrict__ hbB,
    unsigned* __restrict__ cnt, unsigned* __restrict__ gen)
{
  const int bid   = blockIdx.x;
  const int dir   = bid >> 7;
  const int bhalf = (bid >> 6) & 1;
  const int kblk  = bid & 63;

  const float* wih = dir ? wih_b : wih_f;
  const float* whh = dir ? whh_b : whh_f;
  const float* bih = dir ? bih_b : bih_f;
  const float* bhh = dir ? bhh_b : bhh_f;
  float* bufA = dir ? hbA : hfA;
  float* bufB = dir ? hbB : hfB;

  const int tid   = threadIdx.x;
  const int seg8  = tid >> 6;
  const int dseg  = seg8 & 3;
  const int khalf = seg8 >> 2;
  const int lane  = tid & 63;
  const int tx    = lane & 7;
  const int ty    = lane >> 3;
  const int k0    = kblk * 16;
  const int bbase = bhalf * 32;
  const int kloc  = khalf * 8 + ty;      // 0..15
  const int k     = k0 + kloc;
  const int b0    = bbase + tx * 4;

  __shared__ float part[4][4][16][32];

  const float* wr_row = wih + (size_t)k * cR;
  const float* wz_row = wih + (size_t)(cH + k) * cR;
  const float* wn_row = wih + (size_t)(2 * cH + k) * cR;
  const float4* whr = (const float4*)whh + (size_t)k * (cH / 4);
  const float4* whz = (const float4*)whh + (size_t)(cH + k) * (cH / 4);
  const float4* whn = (const float4*)whh + (size_t)(2 * cH + k) * (cH / 4);

  for (int t = 0; t < cT; ++t){
    const float* hin = (t & 1) ? bufB : bufA;
    float*      hout = (t & 1) ? bufA : bufB;
    const int tt = dir ? (cT - 1 - t) : t;
    const float* xin = x + (size_t)tt * cB * cR;

    float ar[4]  = {0.f,0.f,0.f,0.f};
    float az[4]  = {0.f,0.f,0.f,0.f};
    float ani[4] = {0.f,0.f,0.f,0.f};

    // phase 1: x @ w_ih^T (scalar, 389-stride, 4-way d split)
    {
      const float* x0 = xin + (size_t)b0 * cR;
      const int q  = 98;
      const int d0 = dseg * q;
      const int d1 = (d0 + q < cR) ? (d0 + q) : cR;
      #pragma unroll 2
      for (int d = d0; d < d1; ++d){
        const float wr = wr_row[d], wz = wz_row[d], wn = wn_row[d];
        float a[4];
        #pragma unroll
        for (int j = 0; j < 4; ++j) a[j] = x0[(size_t)j * cR + d];
        #pragma unroll
        for (int j = 0; j < 4; ++j){
          ar[j]  = fmaf(a[j], wr, ar[j]);
          az[j]  = fmaf(a[j], wz, az[j]);
          ani[j] = fmaf(a[j], wn, ani[j]);
        }
      }
    }

    // phase 2: h @ w_hh^T (float4, 4-way d split)
    float4 fr[4], fz[4], fnh[4];
    #pragma unroll
    for (int j = 0; j < 4; ++j){ fr[j] = z4(); fz[j] = z4(); fnh[j] = z4(); }
    {
      const float4* h4 = (const float4*)hin;
      const int d40 = dseg * 64;
      const int d41 = d40 + 64;
      #pragma unroll 2
      for (int d4 = d40; d4 < d41; ++d4){
        const float4 wr = whr[d4], wz = whz[d4], wn = whn[d4];
        #pragma unroll
        for (int j = 0; j < 4; ++j){
          const float4 a = h4[(size_t)(b0 + j) * (cH / 4) + d4];
          fma4(fr[j], a, wr); fma4(fz[j], a, wz); fma4(fnh[j], a, wn);
        }
      }
    }

    #pragma unroll
    for (int j = 0; j < 4; ++j){
      const int bl = tx * 4 + j;
      part[dseg][0][kloc][bl] = ar[j] + fold4(fr[j]);
      part[dseg][1][kloc][bl] = az[j] + fold4(fz[j]);
      part[dseg][2][kloc][bl] = ani[j];
      part[dseg][3][kloc][bl] = fold4(fnh[j]);
    }
    __syncthreads();
    {
      const int ke = tid >> 5, bl = tid & 31;   // 16 x 32 = 512 outputs
      float rs = 0.f, zs = 0.f, nis = 0.f, nhs = 0.f;
      #pragma unroll
      for (int s = 0; s < 4; ++s){
        rs  += part[s][0][ke][bl];
        zs  += part[s][1][ke][bl];
        nis += part[s][2][ke][bl];
        nhs += part[s][3][ke][bl];
      }
      const int kk = k0 + ke, bb = bbase + bl;
      const float r  = sigm(rs + bih[kk] + bhh[kk]);
      const float zg = sigm(zs + bih[cH + kk] + bhh[cH + kk]);
      const float nn = tanhf(nis + bih[2 * cH + kk] + r * (nhs + bhh[2 * cH + kk]));
      const float hp = hin[(size_t)bb * cH + kk];
      hout[(size_t)bb * cH + kk] = (1.f - zg) * nn + zg * hp;
    }
    gbar(cnt, gen, NBLK);
  }
}

// ---------------------------------------------------------------- decoder GRU phase
// 512 thr: seg = tid>>6 (8-way d split), lane: tx->4 batches, ty->k (8 rows).
__device__ __forceinline__ void gru_phase512(
    int tid, int k0, int bbase,
    const float* __restrict__ in, int inLf4,
    const float* __restrict__ hprev,
    const float* __restrict__ wih, const float* __restrict__ whh,
    const float* __restrict__ bih, const float* __restrict__ bhh,
    float* __restrict__ hout,
    float (&part)[8][4][8][32])
{
  const int seg  = tid >> 6;
  const int lane = tid & 63;
  const int tx   = lane & 7;
  const int ty   = lane >> 3;
  const int k  = k0 + ty;
  const int b0 = bbase + tx * 4;

  float4 fr[4], fz[4], fni[4], fnh[4];
  #pragma unroll
  for (int j = 0; j < 4; ++j){ fr[j] = z4(); fz[j] = z4(); fni[j] = z4(); fnh[j] = z4(); }

  // phase 1: in @ w_ih^T
  {
    const float4* in4 = (const float4*)in;
    const float4* wir = (const float4*)wih + (size_t)k * inLf4;
    const float4* wiz = (const float4*)wih + (size_t)(cH + k) * inLf4;
    const float4* win = (const float4*)wih + (size_t)(2 * cH + k) * inLf4;
    const int q4 = (inLf4 + 7) >> 3;
    const int d0 = seg * q4;
    const int d1 = (d0 + q4 < inLf4) ? (d0 + q4) : inLf4;
    #pragma unroll 2
    for (int d4 = d0; d4 < d1; ++d4){
      const float4 wr = wir[d4], wz = wiz[d4], wn = win[d4];
      #pragma unroll
      for (int j = 0; j < 4; ++j){
        const float4 a = in4[(size_t)(b0 + j) * inLf4 + d4];
        fma4(fr[j], a, wr); fma4(fz[j], a, wz); fma4(fni[j], a, wn);
      }
    }
  }
  // phase 2: hprev @ w_hh^T
  {
    const float4* h4  = (const float4*)hprev;
    const float4* whr = (const float4*)whh + (size_t)k * (cH / 4);
    const float4* whz = (const float4*)whh + (size_t)(cH + k) * (cH / 4);
    const float4* whn = (const float4*)whh + (size_t)(2 * cH + k) * (cH / 4);
    const int d40 = seg * 32;
    const int d41 = d40 + 32;
    #pragma unroll 2
    for (int d4 = d40; d4 < d41; ++d4){
      const float4 wr = whr[d4], wz = whz[d4], wn = whn[d4];
      #pragma unroll
      for (int j = 0; j < 4; ++j){
        const float4 a = h4[(size_t)(b0 + j) * (cH / 4) + d4];
        fma4(fr[j], a, wr); fma4(fz[j], a, wz); fma4(fnh[j], a, wn);
      }
    }
  }

  #pragma unroll
  for (int j = 0; j < 4; ++j){
    const int bl = tx * 4 + j;
    part[seg][0][ty][bl] = fold4(fr[j]);
    part[seg][1][ty][bl] = fold4(fz[j]);
    part[seg][2][ty][bl] = fold4(fni[j]);
    part[seg][3][ty][bl] = fold4(fnh[j]);
  }
  __syncthreads();
  if (tid < 256){
    const int ke = tid >> 5, bl = tid & 31;   // 8 x 32 outputs
    float rs = 0.f, zs = 0.f, nis = 0.f, nhs = 0.f;
    #pragma unroll
    for (int s = 0; s < 8; ++s){
      rs  += part[s][0][ke][bl];
      zs  += part[s][1][ke][bl];
      nis += part[s][2][ke][bl];
      nhs += part[s][3][ke][bl];
    }
    const int kk = k0 + ke, bb = bbase + bl;
    const float r  = sigm(rs + bih[kk] + bhh[kk]);
    const float zg = sigm(zs + bih[cH + kk] + bhh[cH + kk]);
    const float nn = tanhf(nis + bih[2 * cH + kk] + r * (nhs + bhh[2 * cH + kk]));
    const float hp = hprev[(size_t)bb * cH + kk];
    hout[(size_t)bb * cH + kk] = (1.f - zg) * nn + zg * hp;
  }
}

// ---------------------------------------------------------------- decoder (persistent)
// 256 blocks x 512 thr: kblk = bid>>1 (8 k-rows), bhalf = bid&1. Out-phase on blocks 0..63.
__global__ __launch_bounds__(512, 2) void dec_persist(
    const float* __restrict__ x,
    const float* __restrict__ hfA, const float* __restrict__ hbA,
    const float* __restrict__ w_mu, const float* __restrict__ b_mu,
    const float* __restrict__ w_init, const float* __restrict__ b_init,
    const float* __restrict__ wp0,   const float* __restrict__ w_hh0,
    const float* __restrict__ b_ih0, const float* __restrict__ b_hh0,
    const float* __restrict__ w_ih1, const float* __restrict__ w_hh1,
    const float* __restrict__ b_ih1, const float* __restrict__ b_hh1,
    const float* __restrict__ w_ih2, const float* __restrict__ w_hh2,
    const float* __restrict__ b_ih2, const float* __restrict__ b_hh2,
    const float* __restrict__ w_out, const float* __restrict__ b_out,
    float* __restrict__ h0A, float* __restrict__ h0B,
    float* __restrict__ h1A, float* __restrict__ h1B,
    float* __restrict__ h2A, float* __restrict__ h2B,
    float* __restrict__ inp, float* __restrict__ dout,
    unsigned* __restrict__ cnt, unsigned* __restrict__ gen)
{
  const int bid   = blockIdx.x;
  const int tid   = threadIdx.x;
  const int kblk  = bid >> 1;
  const int bhalf = bid & 1;
  const int k0    = kblk * 8;
  const int bbase = bhalf * 32;

  __shared__ float part[8][4][8][32];
  __shared__ alignas(16) float hl[2 * cH];
  __shared__ alignas(16) float zl[cZ];
  __shared__ float lg[cPF];
  __shared__ float gmax[3], glse[3];
  __shared__ float wbest[8];
  __shared__ int   wbidx[8];
  __shared__ int   amax_s;

  // ---- prologue: latent + hinit + inp init (blocks 0..63, one per batch row)
  if (bid < cB){
    const int b = bid;
    if (tid < 256) ((float4*)hl)[tid]       = ((const float4*)(hfA + (size_t)b * cH))[tid];
    else           ((float4*)hl)[tid]       = ((const float4*)(hbA + (size_t)b * cH))[tid - 256];
    __syncthreads();
    if (tid < cZ){
      const float4* h4 = (const float4*)hl;
      const float4* wr = (const float4*)(w_mu + (size_t)tid * 2 * cH);
      float4 s4 = z4();
      #pragma unroll 4
      for (int i = 0; i < 512; ++i) fma4(s4, h4[i], wr[i]);
      zl[tid] = b_mu[tid] + fold4(s4) * INV_S;
    }
    __syncthreads();
    {
      const float4* zv = (const float4*)zl;
      for (int kk = tid; kk < cH; kk += 512){
        const float4* wr = (const float4*)(w_init + (size_t)kk * cZ);
        float4 s4 = z4();
        #pragma unroll 4
        for (int i = 0; i < 64; ++i) fma4(s4, zv[i], wr[i]);
        h0A[(size_t)b * cH + kk] = tanhf(b_init[kk] + fold4(s4));
      }
      for (int c = tid; c < ISTR; c += 512){
        float v;
        if (c < cPF)            v = (c == cPF - 1) ? 1.f : 0.f;
        else if (c < cPF + cSC) v = (c == cPF + cSC - 1) ? 1.f : 0.f;
        else if (c < cIN0)      v = zl[c - (cPF + cSC)];
        else                    v = 0.f;
        inp[(size_t)b * ISTR + c] = v;
      }
    }
  }
  gbar(cnt, gen, NBLK);

  // ---- main loop
  for (int j = 0; j < cT; ++j){
    const int par = j & 1;
    const float* h0p = par ? h0B : h0A;  float* h0n = par ? h0A : h0B;
    const float* h1p = par ? h1B : h1A;  float* h1n = par ? h1A : h1B;
    const float* h2p = par ? h2B : h2A;  float* h2n = par ? h2A : h2B;

    gru_phase512(tid, k0, bbase, inp, ISTR / 4, h0p,
                 wp0, w_hh0, b_ih0, b_hh0, h0n, part);
    gbar(cnt, gen, NBLK);
    gru_phase512(tid, k0, bbase, h0n, cH / 4, (j == 0 ? h0n : h1p),
                 w_ih1, w_hh1, b_ih1, b_hh1, h1n, part);
    gbar(cnt, gen, NBLK);
    gru_phase512(tid, k0, bbase, h1n, cH / 4, (j == 0 ? h1n : h2p),
                 w_ih2, w_hh2, b_ih2, b_hh2, h2n, part);
    gbar(cnt, gen, NBLK);

    if (bid < cB){
      const int b = bid;
      if (tid < 256) ((float4*)hl)[tid] = ((const float4*)(h2n + (size_t)b * cH))[tid];
      __syncthreads();

      const float4* h4 = (const float4*)hl;
      for (int p = tid; p < cPF; p += 512){
        const float4* wr = (const float4*)(w_out + (size_t)p * cH);
        float4 s4 = z4();
        #pragma unroll 4
        for (int i = 0; i < 256; ++i) fma4(s4, h4[i], wr[i]);
        lg[p] = b_out[p] + fold4(s4);
      }
      __syncthreads();

      const int w = tid >> 6, l = tid & 63;
      if (w < 3){
        float m = -INFINITY;
        for (int p = w * 100 + l; p < w * 100 + 100; p += 64) m = fmaxf(m, lg[p]);
        #pragma unroll
        for (int off = 32; off > 0; off >>= 1) m = fmaxf(m, __shfl_xor(m, off));
        float s = 0.f;
        for (int p = w * 100 + l; p < w * 100 + 100; p += 64) s += expf(lg[p] - m);
        #pragma unroll
        for (int off = 32; off > 0; off >>= 1) s += __shfl_xor(s, off);
        if (l == 0){ gmax[w] = m; glse[w] = logf(s); }
      }
      __syncthreads();

      float best = -INFINITY; int bidx = 0x7fffffff;
      for (int p = tid; p < cPF; p += 512){
        const int g = (p >= 200) ? 2 : ((p >= 100) ? 1 : 0);
        const float o = lg[p] - gmax[g] - glse[g];
        dout[((size_t)b * cT + j) * cPF + p] = o;
        if (o > best || (o == best && p < bidx)){ best = o; bidx = p; }
      }
      #pragma unroll
      for (int off = 32; off > 0; off >>= 1){
        const float ob = __shfl_xor(best, off);
        const int   oi = __shfl_xor(bidx, off);
        if (ob > best || (ob == best && oi < bidx)){ best = ob; bidx = oi; }
      }
      if (l == 0){ wbest[w] = best; wbidx[w] = bidx; }
      __syncthreads();
      if (tid == 0){
        float bb = wbest[0]; int bi = wbidx[0];
        #pragma unroll
        for (int q = 1; q < 8; ++q)
          if (wbest[q] > bb || (wbest[q] == bb && wbidx[q] < bi)){ bb = wbest[q]; bi = wbidx[q]; }
        amax_s = bi;
      }
      __syncthreads();

      const int am = amax_s;
      for (int p = tid; p < cPF; p += 512) inp[(size_t)b * ISTR + p] = (p == am) ? 1.f : 0.f;
      if (tid < cSC) inp[(size_t)b * ISTR + cPF + tid] = x[((size_t)j * cB + b) * cR + tid];
    }
    gbar(cnt, gen, NBLK);
  }
}

} // namespace

// ---------------------------------------------------------------- host
extern "C" void kernel_launch(void* const* d_in, const int* in_sizes, int n_in,
                              void* d_out, int out_size, void* d_ws, size_t ws_size,
                              hipStream_t stream)
{
  const float* x     = (const float*)d_in[0];
  const float* wih_f = (const float*)d_in[2];
  const float* whh_f = (const float*)d_in[3];
  const float* bih_f = (const float*)d_in[4];
  const float* bhh_f = (const float*)d_in[5];
  const float* wih_b = (const float*)d_in[6];
  const float* whh_b = (const float*)d_in[7];
  const float* bih_b = (const float*)d_in[8];
  const float* bhh_b = (const float*)d_in[9];
  const float* w_mu  = (const float*)d_in[10];
  const float* b_mu  = (const float*)d_in[11];
  const float* w_init= (const float*)d_in[14];
  const float* b_init= (const float*)d_in[15];
  const float* w_ih0 = (const float*)d_in[16];
  const float* w_hh0 = (const float*)d_in[17];
  const float* b_ih0 = (const float*)d_in[18];
  const float* b_hh0 = (const float*)d_in[19];
  const float* w_ih1 = (const float*)d_in[20];
  const float* w_hh1 = (const float*)d_in[21];
  const float* b_ih1 = (const float*)d_in[22];
  const float* b_hh1 = (const float*)d_in[23];
  const float* w_ih2 = (const float*)d_in[24];
  const float* w_hh2 = (const float*)d_in[25];
  const float* b_ih2 = (const float*)d_in[26];
  const float* b_hh2 = (const float*)d_in[27];
  const float* w_out = (const float*)d_in[28];
  const float* b_out = (const float*)d_in[29];
  float* dout = (float*)d_out;

  float* ws = (float*)d_ws;
  float* wp0 = ws;                       ws += (size_t)3 * cH * ISTR;   // padded w_ih0
  float* hfA = ws; ws += cB * cH;  float* hfB = ws; ws += cB * cH;
  float* hbA = ws; ws += cB * cH;  float* hbB = ws; ws += cB * cH;
  float* h0A = ws; ws += cB * cH;  float* h0B = ws; ws += cB * cH;
  float* h1A = ws; ws += cB * cH;  float* h1B = ws; ws += cB * cH;
  float* h2A = ws; ws += cB * cH;  float* h2B = ws; ws += cB * cH;
  float* inp   = ws;               ws += cB * ISTR;
  unsigned* bar = (unsigned*)ws;   ws += 64;          // [0]=cntE [16]=genE [32]=cntD [48]=genD
  unsigned* cntE = bar +  0;
  unsigned* genE = bar + 16;
  unsigned* cntD = bar + 32;
  unsigned* genD = bar + 48;

  init_kernel<<<256, 256, 0, stream>>>(hfA, hbA, dout + (size_t)cB * cT * cPF, bar);
  pad_w0_kernel<<<512, 256, 0, stream>>>(w_ih0, wp0);

  enc_persist<<<NBLK, 512, 0, stream>>>(
      x,
      wih_f, whh_f, bih_f, bhh_f,
      wih_b, whh_b, bih_b, bhh_b,
      hfA, hfB, hbA, hbB, cntE, genE);

  dec_persist<<<NBLK, 512, 0, stream>>>(
      x, hfA, hbA,
      w_mu, b_mu, w_init, b_init,
      wp0, w_hh0, b_ih0, b_hh0,
      w_ih1, w_hh1, b_ih1, b_hh1,
      w_ih2, w_hh2, b_ih2, b_hh2,
      w_out, b_out,
      h0A, h0B, h1A, h1B, h2A, h2B,
      inp, dout, cntD, genD);
}